// Round 1
// baseline (3747.012 us; speedup 1.0000x reference)
//
#include <hip/hip_runtime.h>
#include <hip/hip_cooperative_groups.h>

namespace cg = cooperative_groups;

// Problem constants (match reference setup_inputs)
constexpr int BATCH = 2;
constexpr int NZ = 128, NY = 128, NX = 128;
constexpr int PLANE = NY * NX;          // 16384
constexpr int VOL   = NZ * PLANE;       // 2,097,152  (= 1<<21)
constexpr int TOTAL = BATCH * VOL;      // 4,194,304
constexpr int NROWS = BATCH * NZ * NY;  // 32768
constexpr int SUBSTEPS = 10;
constexpr float DT = 0.1f;              // MICRO_DT

constexpr int GRID_BLOCKS = 1024;
constexpr int ROWS_PER_BLOCK = NROWS / GRID_BLOCKS;  // 32 contiguous rows

__global__ __launch_bounds__(256, 4)
void fk_solver(const float* __restrict__ u0,
               const float* __restrict__ Dm,
               const float* __restrict__ Rm,
               const int*   __restrict__ dt_days,
               float* __restrict__ out,
               float* __restrict__ ws)
{
    cg::grid_group grid = cg::this_grid();

    // Per-batch step counts (dt in [0,4); clamp defensively)
    int d0 = dt_days[0]; d0 = d0 < 0 ? 0 : (d0 > 4 ? 4 : d0);
    int d1 = dt_days[1]; d1 = d1 < 0 ? 0 : (d1 > 4 ? 4 : d1);
    const int steps0 = d0 * SUBSTEPS;
    const int steps1 = d1 * SUBSTEPS;
    const int S = steps0 > steps1 ? steps0 : steps1;

    const int x    = threadIdx.x & (NX - 1);   // lane within row
    const int rsub = threadIdx.x >> 7;         // 0 or 1: two rows per iteration
    const int rowBegin = blockIdx.x * ROWS_PER_BLOCK;

    // Ping-pong: buf[0] = ws, buf[1] = out.
    // steps_b is a multiple of 10, so a batch item's final write (step
    // steps_b-1, odd) always lands in buf[1] == out. Epilogue clips in place.
    float* buf0 = ws;
    float* buf1 = out;

    for (int t = 0; t < S; ++t) {
        const float* __restrict__ src = (t == 0) ? u0 : ((t & 1) ? buf0 : buf1);
        float* __restrict__ dst = (t & 1) ? buf1 : buf0;

        #pragma unroll 1
        for (int r = rsub; r < ROWS_PER_BLOCK; r += 2) {
            const int row = rowBegin + r;
            const int b = row >> 14;                    // row / (NZ*NY)
            const int steps_b = (b == 0) ? steps0 : steps1;
            if (t >= steps_b) continue;                 // this batch item is done

            const int z = (row >> 7) & (NZ - 1);
            const int y = row & (NY - 1);
            const int idx = row * NX + x;

            const float uc = src[idx];
            const float xm = (x > 0)      ? src[idx - 1]     : 0.0f;
            const float xp = (x < NX - 1) ? src[idx + 1]     : 0.0f;
            const float ym = (y > 0)      ? src[idx - NX]    : 0.0f;
            const float yp = (y < NY - 1) ? src[idx + NX]    : 0.0f;
            const float zm = (z > 0)      ? src[idx - PLANE] : 0.0f;
            const float zp = (z < NZ - 1) ? src[idx + PLANE] : 0.0f;

            const float lap = (xm + xp) + (ym + yp) + (zm + zp) - 6.0f * uc;
            const float du  = Dm[idx] * lap + Rm[idx] * uc * (1.0f - uc);
            dst[idx] = fmaf(DT, du, uc);
        }
        grid.sync();
    }

    // Epilogue: clip into out. For steps_b==0 the field never left u0.
    const int tid = blockIdx.x * blockDim.x + threadIdx.x;
    const int nthreads = gridDim.x * blockDim.x;
    for (int i = tid; i < TOTAL; i += nthreads) {
        const int b = i >> 21;                          // i / VOL
        const int steps_b = (b == 0) ? steps0 : steps1;
        float v = (steps_b > 0) ? out[i] : u0[i];
        v = fminf(fmaxf(v, 0.0f), 1.0f);
        out[i] = v;
    }
}

extern "C" void kernel_launch(void* const* d_in, const int* in_sizes, int n_in,
                              void* d_out, int out_size, void* d_ws, size_t ws_size,
                              hipStream_t stream) {
    const float* u0  = (const float*)d_in[0];
    const float* Dm  = (const float*)d_in[1];
    const float* Rm  = (const float*)d_in[2];
    const int*   dtd = (const int*)d_in[3];
    float* out = (float*)d_out;
    float* ws  = (float*)d_ws;   // needs 16 MiB (one ping-pong buffer)

    void* args[] = { (void*)&u0, (void*)&Dm, (void*)&Rm, (void*)&dtd,
                     (void*)&out, (void*)&ws };
    dim3 grid(GRID_BLOCKS), block(256);
    hipLaunchCooperativeKernel((const void*)fk_solver, grid, block, args, 0, stream);
}

// Round 2
// 463.532 us; speedup vs baseline: 8.0836x; 8.0836x over previous
//
#include <hip/hip_runtime.h>

// Fisher-Kolmogorov explicit Euler, B=2, 128^3, up to 40 masked micro-steps.
// Strategy: 40 sequential graph-captured launches (HW inter-kernel barrier is
// far cheaper than cg::grid.sync's atomic+L2-flush barrier), float4-vectorized
// stencil, ping-pong ws<->out with "final active step is always odd" parity so
// each batch item's final state lands in d_out with zero copy passes.

constexpr int NX = 128, NY = 128, NZ = 128;
constexpr int PLANE = NX * NY;           // 16384
constexpr int VOL   = NZ * PLANE;        // 2,097,152
constexpr int TOTAL = 2 * VOL;           // 4,194,304
constexpr int NQ    = TOTAL / 4;         // 1,048,576 float4 cells
constexpr int BLOCKS = NQ / 256;         // 4096
constexpr float DT = 0.1f;               // MICRO_DT
constexpr int MAX_STEPS = 40;            // MAX_DAYS * SUBSTEPS

__global__ __launch_bounds__(256)
void fk_step(const float* __restrict__ src, float* __restrict__ dst,
             const float* __restrict__ Dm, const float* __restrict__ Rm,
             const int* __restrict__ dtd, int t)
{
    const int i4  = blockIdx.x * 256 + threadIdx.x;  // [0, NQ)
    const int row = i4 >> 5;                         // 32 float4 per row
    const int b   = row >> 14;                       // batch item (blocks never straddle)

    int d = dtd[b];
    d = d < 0 ? 0 : (d > 4 ? 4 : d);
    if (t >= d * 10) return;                         // wave-uniform early exit

    const int xg  = i4 & 31;
    const int y   = row & (NY - 1);
    const int z   = (row >> 7) & (NZ - 1);
    const int idx = i4 << 2;

    const float4 c  = *(const float4*)(src + idx);
    const float lft = (xg > 0)      ? src[idx - 1] : 0.0f;
    const float rgt = (xg < 31)     ? src[idx + 4] : 0.0f;
    const float4 zero = make_float4(0.f, 0.f, 0.f, 0.f);
    const float4 ym = (y > 0)       ? *(const float4*)(src + idx - NX)    : zero;
    const float4 yp = (y < NY - 1)  ? *(const float4*)(src + idx + NX)    : zero;
    const float4 zm = (z > 0)       ? *(const float4*)(src + idx - PLANE) : zero;
    const float4 zp = (z < NZ - 1)  ? *(const float4*)(src + idx + PLANE) : zero;
    const float4 Dv = *(const float4*)(Dm + idx);
    const float4 Rv = *(const float4*)(Rm + idx);

    float4 o;
    {
        const float lap = (lft + c.y) + (ym.x + yp.x) + (zm.x + zp.x) - 6.0f * c.x;
        const float du  = fmaf(Dv.x, lap, Rv.x * c.x * (1.0f - c.x));
        o.x = fmaf(DT, du, c.x);
    }
    {
        const float lap = (c.x + c.z) + (ym.y + yp.y) + (zm.y + zp.y) - 6.0f * c.y;
        const float du  = fmaf(Dv.y, lap, Rv.y * c.y * (1.0f - c.y));
        o.y = fmaf(DT, du, c.y);
    }
    {
        const float lap = (c.y + c.w) + (ym.z + yp.z) + (zm.z + zp.z) - 6.0f * c.z;
        const float du  = fmaf(Dv.z, lap, Rv.z * c.z * (1.0f - c.z));
        o.z = fmaf(DT, du, c.z);
    }
    {
        const float lap = (c.z + rgt) + (ym.w + yp.w) + (zm.w + zp.w) - 6.0f * c.w;
        const float du  = fmaf(Dv.w, lap, Rv.w * c.w * (1.0f - c.w));
        o.w = fmaf(DT, du, c.w);
    }
    *(float4*)(dst + idx) = o;
}

__global__ __launch_bounds__(256)
void fk_clip(const float* __restrict__ u0, float* __restrict__ out,
             const int* __restrict__ dtd)
{
    const int i4 = blockIdx.x * 256 + threadIdx.x;   // [0, NQ)
    const int b  = i4 >> 19;                         // NQ/2 = 1<<19 per batch
    int d = dtd[b];
    d = d < 0 ? 0 : (d > 4 ? 4 : d);
    // For steps==0 the field never left u0 (step kernels wrote nothing).
    const float4 v = (d > 0) ? ((const float4*)out)[i4] : ((const float4*)u0)[i4];
    float4 o;
    o.x = fminf(fmaxf(v.x, 0.0f), 1.0f);
    o.y = fminf(fmaxf(v.y, 0.0f), 1.0f);
    o.z = fminf(fmaxf(v.z, 0.0f), 1.0f);
    o.w = fminf(fmaxf(v.w, 0.0f), 1.0f);
    ((float4*)out)[i4] = o;
}

extern "C" void kernel_launch(void* const* d_in, const int* in_sizes, int n_in,
                              void* d_out, int out_size, void* d_ws, size_t ws_size,
                              hipStream_t stream) {
    const float* u0  = (const float*)d_in[0];
    const float* Dm  = (const float*)d_in[1];
    const float* Rm  = (const float*)d_in[2];
    const int*   dtd = (const int*)d_in[3];
    float* out = (float*)d_out;
    float* ws  = (float*)d_ws;   // 16 MiB ping-pong buffer (buf0)

    // Ping-pong parity: t even -> dst = ws (buf0); t odd -> dst = out (buf1).
    // steps_b is a multiple of 10, so each active batch item's final write
    // (t = steps_b-1, odd) lands in out. Inactive steps write nothing.
    for (int t = 0; t < MAX_STEPS; ++t) {
        const float* src = (t == 0) ? u0 : ((t & 1) ? ws : out);
        float* dst = (t & 1) ? out : ws;
        fk_step<<<BLOCKS, 256, 0, stream>>>(src, dst, Dm, Rm, dtd, t);
    }
    fk_clip<<<BLOCKS, 256, 0, stream>>>(u0, out, dtd);
}

// Round 3
// 286.307 us; speedup vs baseline: 13.0874x; 1.6190x over previous
//
#include <hip/hip_runtime.h>

// Fisher-Kolmogorov explicit Euler, B=2, 128^3, up to 40 masked micro-steps.
// 40 sequential graph-captured launches + clip. Round-3 change: z-blocking —
// each thread computes 4 z-consecutive float4 cells, sharing 6 u-planes in
// registers (each plane is both "center" and "z-neighbor"), quadrupling
// per-wave outstanding loads to attack the latency bound seen in round 2.

constexpr int NX = 128, NY = 128, NZ = 128;
constexpr int PLANE = NX * NY;           // 16384
constexpr int VOL   = NZ * PLANE;        // 2,097,152
constexpr int TOTAL = 2 * VOL;           // 4,194,304
constexpr int NQ    = TOTAL / 4;         // 1,048,576 float4 cells
constexpr int ZB    = 4;                 // z-cells per thread
constexpr int NTHREADS = NQ / ZB;        // 262,144
constexpr int STEP_BLOCKS = NTHREADS / 256;  // 1024
constexpr int CLIP_BLOCKS = NQ / 256;        // 4096
constexpr float DT = 0.1f;               // MICRO_DT
constexpr int MAX_STEPS = 40;            // MAX_DAYS * SUBSTEPS

__device__ __forceinline__ float4 ld4(const float* p) {
    return *(const float4*)p;
}

__global__ __launch_bounds__(256)
void fk_step(const float* __restrict__ src, float* __restrict__ dst,
             const float* __restrict__ Dm, const float* __restrict__ Rm,
             const int* __restrict__ dtd, int t)
{
    const int tid = blockIdx.x * 256 + threadIdx.x;   // [0, NTHREADS)
    const int b   = tid >> 17;                        // batch item

    int d = dtd[b];
    d = d < 0 ? 0 : (d > 4 ? 4 : d);
    if (t >= d * 10) return;                          // wave-uniform early exit

    const int xq = tid & 31;                          // float4 index within row
    const int y  = (tid >> 5) & (NY - 1);
    const int zb = (tid >> 12) & 31;                  // z-block of 4
    const int z0 = zb * ZB;
    const int base = (b << 21) + z0 * PLANE + y * NX + (xq << 2);

    const float4 zero = make_float4(0.f, 0.f, 0.f, 0.f);

    // u planes z0-1 .. z0+4 (Dirichlet zero outside the domain)
    float4 up[ZB + 2];
    #pragma unroll
    for (int j = 0; j < ZB + 2; ++j) {
        const int z = z0 - 1 + j;
        up[j] = (z >= 0 && z < NZ) ? ld4(src + base + (j - 1) * PLANE) : zero;
    }

    // y/x neighbor + coefficient loads for all 4 cells (independent -> MLP)
    float4 ym[ZB], yp[ZB], Dv[ZB], Rv[ZB];
    float lft[ZB], rgt[ZB];
    const bool has_ym = (y > 0), has_yp = (y < NY - 1);
    const bool has_l = (xq > 0), has_r = (xq < 31);
    #pragma unroll
    for (int k = 0; k < ZB; ++k) {
        const int idx = base + k * PLANE;
        ym[k] = has_ym ? ld4(src + idx - NX) : zero;
        yp[k] = has_yp ? ld4(src + idx + NX) : zero;
        lft[k] = has_l ? src[idx - 1] : 0.0f;
        rgt[k] = has_r ? src[idx + 4] : 0.0f;
        Dv[k] = ld4(Dm + idx);
        Rv[k] = ld4(Rm + idx);
    }

    #pragma unroll
    for (int k = 0; k < ZB; ++k) {
        const float4 c  = up[k + 1];
        const float4 zm = up[k];
        const float4 zp = up[k + 2];
        float4 o;
        {
            const float lap = (lft[k] + c.y) + (ym[k].x + yp[k].x) + (zm.x + zp.x) - 6.0f * c.x;
            o.x = fmaf(DT, fmaf(Dv[k].x, lap, Rv[k].x * c.x * (1.0f - c.x)), c.x);
        }
        {
            const float lap = (c.x + c.z) + (ym[k].y + yp[k].y) + (zm.y + zp.y) - 6.0f * c.y;
            o.y = fmaf(DT, fmaf(Dv[k].y, lap, Rv[k].y * c.y * (1.0f - c.y)), c.y);
        }
        {
            const float lap = (c.y + c.w) + (ym[k].z + yp[k].z) + (zm.z + zp.z) - 6.0f * c.z;
            o.z = fmaf(DT, fmaf(Dv[k].z, lap, Rv[k].z * c.z * (1.0f - c.z)), c.z);
        }
        {
            const float lap = (c.z + rgt[k]) + (ym[k].w + yp[k].w) + (zm.w + zp.w) - 6.0f * c.w;
            o.w = fmaf(DT, fmaf(Dv[k].w, lap, Rv[k].w * c.w * (1.0f - c.w)), c.w);
        }
        *(float4*)(dst + base + k * PLANE) = o;
    }
}

__global__ __launch_bounds__(256)
void fk_clip(const float* __restrict__ u0, float* __restrict__ out,
             const int* __restrict__ dtd)
{
    const int i4 = blockIdx.x * 256 + threadIdx.x;   // [0, NQ)
    const int b  = i4 >> 19;                         // NQ/2 = 1<<19 per batch
    int d = dtd[b];
    d = d < 0 ? 0 : (d > 4 ? 4 : d);
    // For steps==0 the field never left u0 (step kernels wrote nothing).
    const float4 v = (d > 0) ? ((const float4*)out)[i4] : ((const float4*)u0)[i4];
    float4 o;
    o.x = fminf(fmaxf(v.x, 0.0f), 1.0f);
    o.y = fminf(fmaxf(v.y, 0.0f), 1.0f);
    o.z = fminf(fmaxf(v.z, 0.0f), 1.0f);
    o.w = fminf(fmaxf(v.w, 0.0f), 1.0f);
    ((float4*)out)[i4] = o;
}

extern "C" void kernel_launch(void* const* d_in, const int* in_sizes, int n_in,
                              void* d_out, int out_size, void* d_ws, size_t ws_size,
                              hipStream_t stream) {
    const float* u0  = (const float*)d_in[0];
    const float* Dm  = (const float*)d_in[1];
    const float* Rm  = (const float*)d_in[2];
    const int*   dtd = (const int*)d_in[3];
    float* out = (float*)d_out;
    float* ws  = (float*)d_ws;   // 16 MiB used as ping-pong buffer (buf0)

    // Ping-pong parity: t even -> dst = ws; t odd -> dst = out. steps_b is a
    // multiple of 10, so each active item's final write (odd t) lands in out.
    for (int t = 0; t < MAX_STEPS; ++t) {
        const float* src = (t == 0) ? u0 : ((t & 1) ? ws : out);
        float* dst = (t & 1) ? out : ws;
        fk_step<<<STEP_BLOCKS, 256, 0, stream>>>(src, dst, Dm, Rm, dtd, t);
    }
    fk_clip<<<CLIP_BLOCKS, 256, 0, stream>>>(u0, out, dtd);
}

// Round 4
// 275.062 us; speedup vs baseline: 13.6224x; 1.0409x over previous
//
#include <hip/hip_runtime.h>
#include <cstdint>

// Fisher-Kolmogorov explicit Euler, B=2, 128^3, up to 40 masked micro-steps.
// Round-4: (a) D,rho packed as interleaved bf16 (one 16B load serves 4 cells'
// D AND rho -> -17% L1 bytes, the round-3 binder), (b) clip fused into the
// final active step per batch item (d==0 handled in the t=0 dispatch), so the
// standalone clip pass is gone.

constexpr int NX = 128, NY = 128, NZ = 128;
constexpr int PLANE = NX * NY;           // 16384
constexpr int VOL   = NZ * PLANE;        // 2,097,152
constexpr int TOTAL = 2 * VOL;           // 4,194,304
constexpr int NQ    = TOTAL / 4;         // 1,048,576 float4 cells
constexpr int ZB    = 4;                 // z-cells per thread
constexpr int NTHREADS = NQ / ZB;        // 262,144
constexpr int STEP_BLOCKS = NTHREADS / 256;  // 1024
constexpr int PACK_BLOCKS = NQ / 256;        // 4096
constexpr float DT = 0.1f;               // MICRO_DT
constexpr int MAX_STEPS = 40;            // MAX_DAYS * SUBSTEPS

__device__ __forceinline__ float4 ld4(const float* p) { return *(const float4*)p; }

__device__ __forceinline__ uint32_t f2bf(float f) {
    uint32_t u = __float_as_uint(f);
    u += 0x7fffu + ((u >> 16) & 1u);     // round-to-nearest-even
    return u >> 16;
}

// Pack per-cell (D, rho) as bf16 pair: lo16 = D, hi16 = rho.
__global__ __launch_bounds__(256)
void fk_pack(const float* __restrict__ Dm, const float* __restrict__ Rm,
             uint32_t* __restrict__ dr)
{
    const int i4  = blockIdx.x * 256 + threadIdx.x;   // [0, NQ)
    const int idx = i4 << 2;
    const float4 Dv = ld4(Dm + idx);
    const float4 Rv = ld4(Rm + idx);
    uint4 o;
    o.x = f2bf(Dv.x) | (f2bf(Rv.x) << 16);
    o.y = f2bf(Dv.y) | (f2bf(Rv.y) << 16);
    o.z = f2bf(Dv.z) | (f2bf(Rv.z) << 16);
    o.w = f2bf(Dv.w) | (f2bf(Rv.w) << 16);
    ((uint4*)dr)[i4] = o;
}

__device__ __forceinline__ float bf_lo(uint32_t p) { return __uint_as_float(p << 16); }
__device__ __forceinline__ float bf_hi(uint32_t p) { return __uint_as_float(p & 0xffff0000u); }
__device__ __forceinline__ float clip01(float v) { return fminf(fmaxf(v, 0.0f), 1.0f); }

__global__ __launch_bounds__(256)
void fk_step(const float* __restrict__ src, float* __restrict__ dst,
             const uint32_t* __restrict__ dr, const int* __restrict__ dtd, int t,
             const float* __restrict__ u0, float* __restrict__ out)
{
    const int tid = blockIdx.x * 256 + threadIdx.x;   // [0, NTHREADS)
    const int b   = tid >> 17;                        // batch item (blocks never straddle)

    int d = dtd[b];
    d = d < 0 ? 0 : (d > 4 ? 4 : d);
    const int steps = d * 10;

    const int xq = tid & 31;                          // float4 index within row
    const int y  = (tid >> 5) & (NY - 1);
    const int zb = (tid >> 12) & 31;                  // z-block of 4
    const int z0 = zb * ZB;
    const int base = (b << 21) + z0 * PLANE + y * NX + (xq << 2);

    if (t >= steps) {
        // d==0 items never get a step write; emit clip(u0) once, at t==0.
        if (steps == 0 && t == 0) {
            #pragma unroll
            for (int k = 0; k < ZB; ++k) {
                const int idx = base + k * PLANE;
                const float4 v = ld4(u0 + idx);
                float4 o;
                o.x = clip01(v.x); o.y = clip01(v.y);
                o.z = clip01(v.z); o.w = clip01(v.w);
                *(float4*)(out + idx) = o;
            }
        }
        return;                                       // wave-uniform
    }
    const bool last = (t == steps - 1);               // final write -> clamp

    const float4 zero = make_float4(0.f, 0.f, 0.f, 0.f);

    // u planes z0-1 .. z0+4 (Dirichlet zero outside the domain)
    float4 up[ZB + 2];
    #pragma unroll
    for (int j = 0; j < ZB + 2; ++j) {
        const int z = z0 - 1 + j;
        up[j] = (z >= 0 && z < NZ) ? ld4(src + base + (j - 1) * PLANE) : zero;
    }

    // y/x neighbor + packed-coefficient loads (independent -> deep MLP)
    float4 ym[ZB], yp[ZB];
    uint4 pr[ZB];
    float lft[ZB], rgt[ZB];
    const bool has_ym = (y > 0), has_yp = (y < NY - 1);
    const bool has_l = (xq > 0), has_r = (xq < 31);
    #pragma unroll
    for (int k = 0; k < ZB; ++k) {
        const int idx = base + k * PLANE;
        ym[k] = has_ym ? ld4(src + idx - NX) : zero;
        yp[k] = has_yp ? ld4(src + idx + NX) : zero;
        lft[k] = has_l ? src[idx - 1] : 0.0f;
        rgt[k] = has_r ? src[idx + 4] : 0.0f;
        pr[k] = *(const uint4*)(dr + idx);            // 4 cells' (D,rho) bf16 pairs
    }

    #pragma unroll
    for (int k = 0; k < ZB; ++k) {
        const float4 c  = up[k + 1];
        const float4 zm = up[k];
        const float4 zp = up[k + 2];
        float4 o;
        {
            const float lap = (lft[k] + c.y) + (ym[k].x + yp[k].x) + (zm.x + zp.x) - 6.0f * c.x;
            o.x = fmaf(DT, fmaf(bf_lo(pr[k].x), lap, bf_hi(pr[k].x) * c.x * (1.0f - c.x)), c.x);
        }
        {
            const float lap = (c.x + c.z) + (ym[k].y + yp[k].y) + (zm.y + zp.y) - 6.0f * c.y;
            o.y = fmaf(DT, fmaf(bf_lo(pr[k].y), lap, bf_hi(pr[k].y) * c.y * (1.0f - c.y)), c.y);
        }
        {
            const float lap = (c.y + c.w) + (ym[k].z + yp[k].z) + (zm.z + zp.z) - 6.0f * c.z;
            o.z = fmaf(DT, fmaf(bf_lo(pr[k].z), lap, bf_hi(pr[k].z) * c.z * (1.0f - c.z)), c.z);
        }
        {
            const float lap = (c.z + rgt[k]) + (ym[k].w + yp[k].w) + (zm.w + zp.w) - 6.0f * c.w;
            o.w = fmaf(DT, fmaf(bf_lo(pr[k].w), lap, bf_hi(pr[k].w) * c.w * (1.0f - c.w)), c.w);
        }
        if (last) {
            o.x = clip01(o.x); o.y = clip01(o.y);
            o.z = clip01(o.z); o.w = clip01(o.w);
        }
        *(float4*)(dst + base + k * PLANE) = o;
    }
}

extern "C" void kernel_launch(void* const* d_in, const int* in_sizes, int n_in,
                              void* d_out, int out_size, void* d_ws, size_t ws_size,
                              hipStream_t stream) {
    const float* u0  = (const float*)d_in[0];
    const float* Dm  = (const float*)d_in[1];
    const float* Rm  = (const float*)d_in[2];
    const int*   dtd = (const int*)d_in[3];
    float* out = (float*)d_out;
    float* ws  = (float*)d_ws;
    // ws layout: [0, 16 MiB) ping-pong u buffer; [16 MiB, 32 MiB) packed DR.
    float*    ping = ws;
    uint32_t* dr   = (uint32_t*)(ws + TOTAL);

    // Re-pack every call (ws is re-poisoned by the harness before each launch).
    fk_pack<<<PACK_BLOCKS, 256, 0, stream>>>(Dm, Rm, dr);

    // Ping-pong parity: t even -> dst = ws; t odd -> dst = out. steps_b is a
    // multiple of 10, so each active item's final (clamped) write lands in out.
    for (int t = 0; t < MAX_STEPS; ++t) {
        const float* src = (t == 0) ? u0 : ((t & 1) ? ping : out);
        float* dst = (t & 1) ? out : ping;
        fk_step<<<STEP_BLOCKS, 256, 0, stream>>>(src, dst, dr, dtd, t, u0, out);
    }
}

// Round 5
// 248.019 us; speedup vs baseline: 15.1078x; 1.1090x over previous
//
#include <hip/hip_runtime.h>
#include <cstdint>

// Fisher-Kolmogorov explicit Euler, B=2, 128^3, up to 40 masked micro-steps.
// Round-5: 2-step temporal fusion per dispatch. Each block computes step-1 on
// a +1-halo region (6z x 10y x 128x) into LDS (intermediate never hits
// global), syncs, computes step-2 on its 4z x 8y x 128x interior. steps=10*d
// is even, so both sub-steps of a pair share one active mask. Each item's
// final pair writes (clipped) to d_out, chosen per-block on device. Pack of
// (D,rho)->bf16 pairs is folded into pair 0 (reads raw, emits dr).

constexpr int NX = 128, NY = 128, NZ = 128;
constexpr int PLANE = NX * NY;            // 16384
constexpr int VOL   = NZ * PLANE;         // 2,097,152
constexpr int TOTAL = 2 * VOL;            // 4,194,304
constexpr float DT  = 0.1f;               // MICRO_DT
constexpr int MAX_PAIRS = 20;             // 40 micro-steps / 2

constexpr int TY = 8, TZ = 4;             // block interior tile (x is full 128)
constexpr int RY = TY + 2, RZ = TZ + 2;   // step-1 region 10 y x 6 z
constexpr int REGION_F4 = RZ * RY * 32;   // 1920 float4 cells
constexpr int BLOCKS = 2 * (NZ / TZ) * (NY / TY);  // 2*32*16 = 1024

__device__ __forceinline__ float4 ld4(const float* p) { return *(const float4*)p; }

__device__ __forceinline__ uint32_t f2bf(float f) {
    uint32_t u = __float_as_uint(f);
    u += 0x7fffu + ((u >> 16) & 1u);      // round-to-nearest-even
    return u >> 16;
}
__device__ __forceinline__ float bf_lo(uint32_t p) { return __uint_as_float(p << 16); }
__device__ __forceinline__ float bf_hi(uint32_t p) { return __uint_as_float(p & 0xffff0000u); }
__device__ __forceinline__ float clip01(float v) { return fminf(fmaxf(v, 0.0f), 1.0f); }

__device__ __forceinline__ float4 fkstep(float4 c, float xm, float xp,
                                         float4 ym, float4 yp,
                                         float4 zm, float4 zp,
                                         float4 Dv, float4 Rv) {
    float4 o;
    o.x = fmaf(DT, fmaf(Dv.x, (xm + c.y) + (ym.x + yp.x) + (zm.x + zp.x) - 6.0f * c.x,
                        Rv.x * c.x * (1.0f - c.x)), c.x);
    o.y = fmaf(DT, fmaf(Dv.y, (c.x + c.z) + (ym.y + yp.y) + (zm.y + zp.y) - 6.0f * c.y,
                        Rv.y * c.y * (1.0f - c.y)), c.y);
    o.z = fmaf(DT, fmaf(Dv.z, (c.y + c.w) + (ym.z + yp.z) + (zm.z + zp.z) - 6.0f * c.z,
                        Rv.z * c.z * (1.0f - c.z)), c.z);
    o.w = fmaf(DT, fmaf(Dv.w, (c.z + xp) + (ym.w + yp.w) + (zm.w + zp.w) - 6.0f * c.w,
                        Rv.w * c.w * (1.0f - c.w)), c.w);
    return o;
}

__global__ __launch_bounds__(256, 4)
void fk_pair(const float* __restrict__ src, float* __restrict__ dst0,
             float* __restrict__ out, const float* __restrict__ u0,
             const float* __restrict__ Dm, const float* __restrict__ Rm,
             uint32_t* __restrict__ dr, const int* __restrict__ dtd, int p)
{
    const int b  = blockIdx.x >> 9;                  // batch item (block-uniform)
    int d = dtd[b]; d = d < 0 ? 0 : (d > 4 ? 4 : d);
    const int steps = d * 10;

    const int zb = (blockIdx.x >> 4) & 31;
    const int yt = blockIdx.x & 15;
    const int z0 = zb * TZ, y0 = yt * TY;
    const int tid = threadIdx.x;
    const int xq  = tid & 31;                        // float4 lane within row
    const int yi  = tid >> 5;                        // 0..7
    const int baseb = b << 21;
    const float4 zero = make_float4(0.f, 0.f, 0.f, 0.f);

    if (2 * p >= steps) {
        // d==0 items never get a step write: emit clip(u0) once, in pair 0.
        if (steps == 0 && p == 0) {
            #pragma unroll
            for (int k = 0; k < TZ; ++k) {
                const int idx = baseb + (z0 + k) * PLANE + (y0 + yi) * NX + (xq << 2);
                const float4 v = ld4(u0 + idx);
                float4 o;
                o.x = clip01(v.x); o.y = clip01(v.y);
                o.z = clip01(v.z); o.w = clip01(v.w);
                *(float4*)(out + idx) = o;
            }
        }
        return;                                      // block-uniform exit
    }
    const bool first = (p == 0);
    const bool last  = (2 * p == steps - 2);
    float* __restrict__ dst = last ? out : dst0;

    __shared__ float s1[RZ * RY * NX];               // 30 KiB step-1 region

    // ---- Phase 1: step-1 on the +1-halo region, straight into LDS ----
    #pragma unroll 2
    for (int it = 0; it < 8; ++it) {
        const int i = tid + it * 256;
        if (i >= REGION_F4) break;
        const int cxq = i & 31;
        const int t2  = i >> 5;                      // rz*RY + ry
        const int ry  = t2 % RY;
        const int rz  = t2 / RY;
        const int y = y0 - 1 + ry;
        const int z = z0 - 1 + rz;
        float4 o = zero;                             // out-of-domain -> 0 (Dirichlet)
        if ((unsigned)y < (unsigned)NY && (unsigned)z < (unsigned)NZ) {
            const int idx = baseb + z * PLANE + y * NX + (cxq << 2);
            const float4 c  = ld4(src + idx);
            const float xm  = (cxq > 0)  ? src[idx - 1] : 0.0f;
            const float xp  = (cxq < 31) ? src[idx + 4] : 0.0f;
            const float4 ym4 = (y > 0)      ? ld4(src + idx - NX)    : zero;
            const float4 yp4 = (y < NY - 1) ? ld4(src + idx + NX)    : zero;
            const float4 zm4 = (z > 0)      ? ld4(src + idx - PLANE) : zero;
            const float4 zp4 = (z < NZ - 1) ? ld4(src + idx + PLANE) : zero;
            float4 Dv, Rv;
            if (first) {
                Dv = ld4(Dm + idx);
                Rv = ld4(Rm + idx);
            } else {
                const uint4 pr = *(const uint4*)(dr + idx);
                Dv.x = bf_lo(pr.x); Dv.y = bf_lo(pr.y); Dv.z = bf_lo(pr.z); Dv.w = bf_lo(pr.w);
                Rv.x = bf_hi(pr.x); Rv.y = bf_hi(pr.y); Rv.z = bf_hi(pr.z); Rv.w = bf_hi(pr.w);
            }
            o = fkstep(c, xm, xp, ym4, yp4, zm4, zp4, Dv, Rv);
        }
        *(float4*)&s1[t2 * NX + (cxq << 2)] = o;
    }
    __syncthreads();

    // ---- Phase 2: step-2 on the interior from LDS ----
    const int ry = yi + 1;
    const int y  = y0 + yi;
    #pragma unroll
    for (int k = 0; k < TZ; ++k) {
        const int rz = k + 1;
        const float* rowc = &s1[(rz * RY + ry) * NX];
        const float4 c = *(const float4*)&rowc[xq << 2];
        // x-neighbors via f4-extract (conflict-free b128 instead of strided b32)
        float xm = 0.0f, xp = 0.0f;
        if (xq > 0)  xm = ((const float4*)&rowc[(xq - 1) << 2])->w;
        if (xq < 31) xp = ((const float4*)&rowc[(xq + 1) << 2])->x;
        const float4 ym4 = *(const float4*)&s1[(rz * RY + ry - 1) * NX + (xq << 2)];
        const float4 yp4 = *(const float4*)&s1[(rz * RY + ry + 1) * NX + (xq << 2)];
        const float4 zm4 = *(const float4*)&s1[((rz - 1) * RY + ry) * NX + (xq << 2)];
        const float4 zp4 = *(const float4*)&s1[((rz + 1) * RY + ry) * NX + (xq << 2)];

        const int idx = baseb + (z0 + k) * PLANE + y * NX + (xq << 2);
        float4 Dv, Rv;
        if (first) {
            Dv = ld4(Dm + idx);
            Rv = ld4(Rm + idx);
            uint4 pk;                                // emit packed dr for pairs >= 1
            pk.x = f2bf(Dv.x) | (f2bf(Rv.x) << 16);
            pk.y = f2bf(Dv.y) | (f2bf(Rv.y) << 16);
            pk.z = f2bf(Dv.z) | (f2bf(Rv.z) << 16);
            pk.w = f2bf(Dv.w) | (f2bf(Rv.w) << 16);
            *(uint4*)(dr + idx) = pk;
        } else {
            const uint4 pr = *(const uint4*)(dr + idx);
            Dv.x = bf_lo(pr.x); Dv.y = bf_lo(pr.y); Dv.z = bf_lo(pr.z); Dv.w = bf_lo(pr.w);
            Rv.x = bf_hi(pr.x); Rv.y = bf_hi(pr.y); Rv.z = bf_hi(pr.z); Rv.w = bf_hi(pr.w);
        }
        float4 o = fkstep(c, xm, xp, ym4, yp4, zm4, zp4, Dv, Rv);
        if (last) {
            o.x = clip01(o.x); o.y = clip01(o.y);
            o.z = clip01(o.z); o.w = clip01(o.w);
        }
        *(float4*)(dst + idx) = o;
    }
}

extern "C" void kernel_launch(void* const* d_in, const int* in_sizes, int n_in,
                              void* d_out, int out_size, void* d_ws, size_t ws_size,
                              hipStream_t stream) {
    const float* u0  = (const float*)d_in[0];
    const float* Dm  = (const float*)d_in[1];
    const float* Rm  = (const float*)d_in[2];
    const int*   dtd = (const int*)d_in[3];
    float* out = (float*)d_out;
    float* ws  = (float*)d_ws;
    // ws layout: [0,16M) buf0, [16M,32M) buf1, [32M,48M) packed DR (ws=256MB).
    float* buf[2] = { ws, ws + TOTAL };
    uint32_t* dr = (uint32_t*)(ws + 2 * TOTAL);

    // Pair p advances steps 2p,2p+1. src: u0 for p=0 else buf[(p-1)&1];
    // normal dst alternates buf[p&1]; an item's LAST pair redirects to `out`
    // (clipped) on-device. d==0 items emit clip(u0) during pair 0.
    for (int p = 0; p < MAX_PAIRS; ++p) {
        const float* src = (p == 0) ? u0 : buf[(p - 1) & 1];
        fk_pair<<<BLOCKS, 256, 0, stream>>>(src, buf[p & 1], out, u0,
                                            Dm, Rm, dr, dtd, p);
    }
}